// Round 13
// baseline (2240.370 us; speedup 1.0000x reference)
//
#include <hip/hip_runtime.h>
#include <float.h>

#define BNI 0.9999950000374997f  /* 1/sqrt(1+1e-5) */

typedef unsigned int v2u __attribute__((ext_vector_type(2)));

__device__ __forceinline__ float sq3(float x, float y, float z) {
  // exact numpy semantics: (x*x + y*y) + z*z, no FMA contraction
  return __fadd_rn(__fadd_rn(__fmul_rn(x, x), __fmul_rn(y, y)), __fmul_rn(z, z));
}

// ---- packed argmax key: (float_bits(v) << 32) | ~idx, as positive f64 ----
// v >= 0 -> positive double; f64 max ordering == u64 ordering.
// Ties in v resolve to larger ~idx == smaller orig idx (numpy first-max).
// Keys globally unique (distinct ~idx).
__device__ __forceinline__ int key_idx(double k) { return ~__double2loint(k); }

template <int CTRL>
__device__ __forceinline__ double dpp_max(double k) {
  union { double d; int i[2]; } u, r;
  u.d = k;
  r.i[0] = __builtin_amdgcn_mov_dpp(u.i[0], CTRL, 0xF, 0xF, true);
  r.i[1] = __builtin_amdgcn_mov_dpp(u.i[1], CTRL, 0xF, 0xF, true);
  return fmax(k, r.d);
}
// 16-group / 32-half swaps via gfx950 permlane (VALU-speed, no DS round-trip).
// With a==b both outputs hold the partner value; max over BOTH is exact.
// Validated bit-exact in rounds 5-12.
__device__ __forceinline__ double pl16_kmax(double k) {
  union { double d; unsigned i[2]; } u; u.d = k;
  v2u a0 = __builtin_amdgcn_permlane16_swap(u.i[0], u.i[0], false, false);
  v2u a1 = __builtin_amdgcn_permlane16_swap(u.i[1], u.i[1], false, false);
  k = fmax(k, __hiloint2double((int)a1[0], (int)a0[0]));
  k = fmax(k, __hiloint2double((int)a1[1], (int)a0[1]));
  return k;
}
__device__ __forceinline__ double pl32_kmax(double k) {
  union { double d; unsigned i[2]; } u; u.d = k;
  v2u a0 = __builtin_amdgcn_permlane32_swap(u.i[0], u.i[0], false, false);
  v2u a1 = __builtin_amdgcn_permlane32_swap(u.i[1], u.i[1], false, false);
  k = fmax(k, __hiloint2double((int)a1[0], (int)a0[0]));
  k = fmax(k, __hiloint2double((int)a1[1], (int)a0[1]));
  return k;
}
// full 64-lane key max, all-lane replicated, all-VALU
__device__ __forceinline__ double wave_max_key(double k) {
  k = dpp_max<0xB1>(k);   // xor 1
  k = dpp_max<0x4E>(k);   // xor 2
  k = dpp_max<0x141>(k);  // row_half_mirror : 4 -> 8
  k = dpp_max<0x140>(k);  // row_mirror      : 8 -> 16
  k = pl16_kmax(k);       // 16-group swap
  k = pl32_kmax(k);       // 32-half swap
  return k;
}

// ---------------- prep: P4[i] = (x,y,z, x^2+y^2+z^2) ----------------
__global__ void k_prep(const float* __restrict__ p, float4* __restrict__ P4, int N) {
  int i = blockIdx.x * blockDim.x + threadIdx.x;
  if (i < N) {
    float x = p[3 * i], y = p[3 * i + 1], z = p[3 * i + 2];
    P4[i] = make_float4(x, y, z, sq3(x, y, z));
  }
}

// ================= fused gather + Morton 8^3 counting sort =================
// One block per batch: gather (optional) -> LDS -> bbox -> hist -> scan ->
// scatter. Scatter order in a cell is nondeterministic; FPS output is
// permutation-invariant (max with original-index tie-break) -> bit-exact.
__device__ __forceinline__ unsigned mpart3(unsigned x) {
  return (x & 1u) | ((x & 2u) << 2) | ((x & 4u) << 4);
}
__device__ __forceinline__ int cell_id(float4 v, const float* bb) {
  int cx = min(max((int)((v.x - bb[0]) * bb[3]), 0), 7);
  int cy = min(max((int)((v.y - bb[1]) * bb[4]), 0), 7);
  int cz = min(max((int)((v.z - bb[2]) * bb[5]), 0), 7);
  return (int)((mpart3(cx) << 2) | (mpart3(cy) << 1) | mpart3(cz));
}

template <int NPTS, bool DOGATHER>
__global__ __launch_bounds__(1024) void k_sortgather(
    const float4* __restrict__ Pin, const int* __restrict__ fpsI, int n_prev,
    float4* __restrict__ Pout, float4* __restrict__ Psort) {
  __shared__ float4 sPts[NPTS];
  __shared__ int sHist[512], sScan[512], sCur[512];
  __shared__ float sBB[6][16];
  __shared__ float sBBf[8];
  const int b = blockIdx.x, tid = threadIdx.x;
  const int lane = tid & 63, wid = tid >> 6;
  for (int i = tid; i < NPTS; i += 1024) {
    float4 v;
    if (DOGATHER) {
      int src = fpsI[(size_t)b * NPTS + i];
      v = Pin[(size_t)b * n_prev + src];
      Pout[(size_t)b * NPTS + i] = v;  // publish gathered points (bit-copy)
    } else {
      v = Pin[(size_t)b * NPTS + i];
    }
    sPts[i] = v;
  }
  if (tid < 512) sHist[tid] = 0;
  __syncthreads();
  float lx = FLT_MAX, hx = -FLT_MAX, ly = FLT_MAX, hy = -FLT_MAX, lz = FLT_MAX, hz = -FLT_MAX;
  for (int i = tid; i < NPTS; i += 1024) {
    float4 v = sPts[i];
    lx = fminf(lx, v.x); hx = fmaxf(hx, v.x);
    ly = fminf(ly, v.y); hy = fmaxf(hy, v.y);
    lz = fminf(lz, v.z); hz = fmaxf(hz, v.z);
  }
#pragma unroll
  for (int off = 1; off < 64; off <<= 1) {
    lx = fminf(lx, __shfl_xor(lx, off)); hx = fmaxf(hx, __shfl_xor(hx, off));
    ly = fminf(ly, __shfl_xor(ly, off)); hy = fmaxf(hy, __shfl_xor(hy, off));
    lz = fminf(lz, __shfl_xor(lz, off)); hz = fmaxf(hz, __shfl_xor(hz, off));
  }
  if (lane == 0) {
    sBB[0][wid] = lx; sBB[1][wid] = hx; sBB[2][wid] = ly;
    sBB[3][wid] = hy; sBB[4][wid] = lz; sBB[5][wid] = hz;
  }
  __syncthreads();
  if (tid == 0) {
    float LX = FLT_MAX, HX = -FLT_MAX, LY = FLT_MAX, HY = -FLT_MAX, LZ = FLT_MAX, HZ = -FLT_MAX;
    for (int w = 0; w < 16; ++w) {
      LX = fminf(LX, sBB[0][w]); HX = fmaxf(HX, sBB[1][w]);
      LY = fminf(LY, sBB[2][w]); HY = fmaxf(HY, sBB[3][w]);
      LZ = fminf(LZ, sBB[4][w]); HZ = fmaxf(HZ, sBB[5][w]);
    }
    float ex = HX - LX, ey = HY - LY, ez = HZ - LZ;
    sBBf[0] = LX; sBBf[1] = LY; sBBf[2] = LZ;
    sBBf[3] = ex > 0.f ? 8.f / ex : 0.f;
    sBBf[4] = ey > 0.f ? 8.f / ey : 0.f;
    sBBf[5] = ez > 0.f ? 8.f / ez : 0.f;
  }
  __syncthreads();
  for (int i = tid; i < NPTS; i += 1024)
    atomicAdd(&sHist[cell_id(sPts[i], sBBf)], 1);
  __syncthreads();
  if (tid < 512) sScan[tid] = sHist[tid];
  __syncthreads();
  for (int d = 1; d < 512; d <<= 1) {
    int v = 0;
    if (tid < 512 && tid >= d) v = sScan[tid - d];
    __syncthreads();
    if (tid < 512) sScan[tid] += v;
    __syncthreads();
  }
  if (tid < 512) sCur[tid] = sScan[tid] - sHist[tid];  // exclusive
  __syncthreads();
  for (int i = tid; i < NPTS; i += 1024) {
    float4 v = sPts[i];
    int pos = atomicAdd(&sCur[cell_id(v, sBBf)], 1);
    Psort[(size_t)b * NPTS + pos] = make_float4(v.x, v.y, v.z, __int_as_float(i));
  }
}

// ============ FPS body — R12 champion + LDS-staged indices ==================
// Wave w owns sorted [w*64*PT,(w+1)*64*PT); wave bbox prune; skip == provable
// no-op (monotone rn ops); unique packed keys -> bit-exact vs numpy.
// sQ: LDS copy of coords indexed by ORIGINAL index (scattered at init).
// sidx: LDS staging for selected indices; flushed once after the loop so NO
// global store (and no vmcnt drain at the barrier) sits on the step chain.
template <int PT, int NW>
__device__ __forceinline__ void fps_body(
    const float4* __restrict__ Psort, const float4* __restrict__ Porig,
    int n, int m, int* __restrict__ out_idx, int b, double* keys /*[2*16]*/,
    float4* sQ, int* sidx) {
  const int tid = threadIdx.x;
  const int lane = tid & 63, wid = tid >> 6;
  const float4* PS = Psort + (size_t)b * n;
  const float4* PO = Porig + (size_t)b * n;

  float px[PT], py[PT], pz[PT], dist[PT];
  int ni[PT];  // ~orig_idx per slot
  const int base = wid * (64 * PT);
#pragma unroll
  for (int k = 0; k < PT; ++k) {
    float4 v = PS[base + k * 64 + lane];
    px[k] = v.x; py[k] = v.y; pz[k] = v.z;
    int oi = __float_as_int(v.w);
    ni[k] = ~oi;
    sQ[oi] = make_float4(v.x, v.y, v.z, 0.f);  // coords by orig idx (bit-copy)
  }
  // wave bbox (one-time)
  float lx = px[0], hx = px[0], ly = py[0], hy = py[0], lz = pz[0], hz = pz[0];
#pragma unroll
  for (int k = 1; k < PT; ++k) {
    lx = fminf(lx, px[k]); hx = fmaxf(hx, px[k]);
    ly = fminf(ly, py[k]); hy = fmaxf(hy, py[k]);
    lz = fminf(lz, pz[k]); hz = fmaxf(hz, pz[k]);
  }
#pragma unroll
  for (int off = 1; off < 64; off <<= 1) {
    lx = fminf(lx, __shfl_xor(lx, off)); hx = fmaxf(hx, __shfl_xor(hx, off));
    ly = fminf(ly, __shfl_xor(ly, off)); hy = fmaxf(hy, __shfl_xor(hy, off));
    lz = fminf(lz, __shfl_xor(lz, off)); hz = fmaxf(hz, __shfl_xor(hz, off));
  }
  if (tid == 0) sidx[0] = 0;

  float4 q0 = PO[0];
  double ck[PT];
#pragma unroll
  for (int k = 0; k < PT; ++k) {
    float d = sq3(__fsub_rn(px[k], q0.x), __fsub_rn(py[k], q0.y), __fsub_rn(pz[k], q0.z));
    dist[k] = d;
    ck[k] = __hiloint2double(__float_as_int(d), ni[k]);
  }
#pragma unroll
  for (int s = 1; s < PT; s <<= 1)  // exact tree reorder of max over unique keys
#pragma unroll
    for (int k = 0; k + s < PT; k += 2 * s) ck[k] = fmax(ck[k], ck[k + s]);
  double wkey = wave_max_key(ck[0]);

  for (int t = 1; t < m; ++t) {
    int buf = t & 1;  // double-buffered publish -> single barrier per step
    if (lane == 0) keys[buf * 16 + wid] = wkey;
    __syncthreads();
    double kb = keys[buf * 16 + (lane & (NW - 1))];  // replicated broadcast read
    if (NW >= 2)  kb = dpp_max<0xB1>(kb);
    if (NW >= 4)  kb = dpp_max<0x4E>(kb);
    if (NW >= 8)  kb = dpp_max<0x141>(kb);
    if (NW >= 16) kb = dpp_max<0x140>(kb);
    int wi = key_idx(kb);
    if (tid == 0) sidx[t] = wi;  // LDS stage -> no vmcnt at any barrier
    if (t + 1 >= m) break;
    float4 qq = sQ[wi];  // uniform LDS broadcast read (init scatter, pre-barrier)
    // exact lower bound of d2 from this wave's bbox to qq (monotone rn ops)
    float tx = fmaxf(fmaxf(__fsub_rn(lx, qq.x), __fsub_rn(qq.x, hx)), 0.f);
    float ty = fmaxf(fmaxf(__fsub_rn(ly, qq.y), __fsub_rn(qq.y, hy)), 0.f);
    float tz = fmaxf(fmaxf(__fsub_rn(lz, qq.z), __fsub_rn(qq.z, hz)), 0.f);
    float lb = sq3(tx, ty, tz);
    float wv = __uint_as_float((unsigned)__double2hiint(wkey));
    if (lb < wv) {  // wave-uniform; prune == provable no-op
      double ck2[PT];
#pragma unroll
      for (int k = 0; k < PT; ++k) {
        float d = sq3(__fsub_rn(px[k], qq.x), __fsub_rn(py[k], qq.y), __fsub_rn(pz[k], qq.z));
        float nd = fminf(dist[k], d);
        dist[k] = nd;
        ck2[k] = __hiloint2double(__float_as_int(nd), ni[k]);
      }
#pragma unroll
      for (int s = 1; s < PT; s <<= 1)
#pragma unroll
        for (int k = 0; k + s < PT; k += 2 * s) ck2[k] = fmax(ck2[k], ck2[k + s]);
      wkey = wave_max_key(ck2[0]);
    }
  }
  __syncthreads();
  for (int i = tid; i < m; i += 64 * NW)
    out_idx[(size_t)b * m + i] = sidx[i];
}

// ---------------- enc1 body (elementwise, used by combo0 extra blocks) -------
__device__ __forceinline__ void enc1_body(
    const float* __restrict__ p0, const float* __restrict__ x0,
    const float* __restrict__ W, const float* __restrict__ g,
    const float* __restrict__ bt, float* __restrict__ X, int N, int t) {
  int pt = t >> 5, c = t & 31;
  if (pt >= N) return;
  float i0 = p0[pt * 3], i1 = p0[pt * 3 + 1], i2 = p0[pt * 3 + 2];
  float i3 = x0[pt * 3], i4 = x0[pt * 3 + 1], i5 = x0[pt * 3 + 2];
  float a = i0 * W[c] + i1 * W[32 + c] + i2 * W[64 + c] +
            i3 * W[96 + c] + i4 * W[128 + c] + i5 * W[160 + c];
  a = a * (g[c] * BNI) + bt[c];
  X[(size_t)pt * 32 + c] = fmaxf(a, 0.f);
}

// ---------------- KNN body: one wave per query; exact expanded-form d2 -------
__device__ void knn_body(const float4* __restrict__ Pq, const float4* __restrict__ Pc,
                         int n, int m, int* __restrict__ knn, int gw) {
  int lane = threadIdx.x & 63;
  int b = gw / m;
  float4 q = Pq[gw];
  const float4* C = Pc + (size_t)b * n;
  float ad[8];
  int ai[8];
#pragma unroll
  for (int s = 0; s < 8; ++s) { ad[s] = FLT_MAX; ai[s] = 0x7fffffff; }
  for (int j = lane; j < n; j += 64) {
    float4 c = C[j];
    float dot = __fadd_rn(__fadd_rn(__fmul_rn(q.x, c.x), __fmul_rn(q.y, c.y)), __fmul_rn(q.z, c.z));
    float d2 = __fsub_rn(__fadd_rn(q.w, c.w), __fmul_rn(2.f, dot));  // (qq+pp) - 2*dot
    if (d2 < ad[7] || (d2 == ad[7] && j < ai[7])) {
      float cd = d2; int ci = j;
#pragma unroll
      for (int s = 0; s < 8; ++s) {
        bool sw = (cd < ad[s]) || (cd == ad[s] && ci < ai[s]);
        float td = ad[s]; int ti = ai[s];
        ad[s] = sw ? cd : td; ai[s] = sw ? ci : ti;
        cd = sw ? td : cd;  ci = sw ? ti : ci;
      }
    }
  }
  int pos = 0;
  int* kout = knn + (size_t)gw * 8;
#pragma unroll
  for (int r = 0; r < 8; ++r) {
    float hv = FLT_MAX; int hi = 0x7fffffff;
#pragma unroll
    for (int s = 7; s >= 0; --s)
      if (pos == s) { hv = ad[s]; hi = ai[s]; }
    float v = hv; int ix = hi;
#pragma unroll
    for (int off = 1; off < 64; off <<= 1) {
      float ov = __shfl_xor(v, off);
      int oi = __shfl_xor(ix, off);
      if (ov < v || (ov == v && oi < ix)) { v = ov; ix = oi; }
    }
    if (hv == v && hi == ix) pos++;  // unique owner (point indices unique)
    if (lane == 0) kout[r] = ix;
  }
}

// ------- feat body: NQ = NT/COUT queries per block, same math as before ------
template <int CINF, int COUT, int NT>
__device__ __forceinline__ void feat_body(
    const float4* __restrict__ Pq, const float4* __restrict__ Pc,
    const float* __restrict__ Xin, const int* __restrict__ knn,
    const float* __restrict__ W, const float* __restrict__ g,
    const float* __restrict__ bt, float* __restrict__ Xout,
    int n, int m, int bi0, int total, char* smem) {
  constexpr int F = 3 + CINF;
  constexpr int NQ = NT / COUT;
  typedef float SF[8][F];
  SF* sf = (SF*)smem;
  int tid = threadIdx.x;
  if (tid < NQ * 8) {
    int ql = tid >> 3, k = tid & 7;
    int bi = bi0 + ql;
    if (bi < total) {
      float4 q = Pq[bi];
      int b = bi / m;
      int nb = knn[(size_t)bi * 8 + k];
      float4 c = Pc[(size_t)b * n + nb];
      sf[ql][k][0] = c.x - q.x;
      sf[ql][k][1] = c.y - q.y;
      sf[ql][k][2] = c.z - q.z;
    }
  }
  for (int e = tid; e < NQ * 8 * CINF; e += NT) {
    int ql = e / (8 * CINF);
    int r = e - ql * (8 * CINF);
    int k = r / CINF, j = r - k * CINF;
    int bi = bi0 + ql;
    if (bi < total) {
      int b = bi / m;
      int nb = knn[(size_t)bi * 8 + k];
      sf[ql][k][3 + j] = Xin[((size_t)b * n + nb) * CINF + j];
    }
  }
  __syncthreads();
  int ql = tid / COUT, c = tid - ql * COUT;
  int bi = bi0 + ql;
  if (bi >= total) return;
  float acc[8] = {0.f, 0.f, 0.f, 0.f, 0.f, 0.f, 0.f, 0.f};
  for (int j = 0; j < F; ++j) {
    float w = W[(size_t)j * COUT + c];
#pragma unroll
    for (int k = 0; k < 8; ++k) acc[k] = fmaf(sf[ql][k][j], w, acc[k]);
  }
  float sc = g[c] * BNI, bb = bt[c];
  float mx = 0.f;
#pragma unroll
  for (int k = 0; k < 8; ++k) mx = fmaxf(mx, fmaf(acc[k], sc, bb));
  Xout[(size_t)bi * COUT + c] = mx;
}

// ======================= fused heterogeneous kernels =========================
// combo0: fps2 (blocks 0..B-1) || enc1
__global__ __launch_bounds__(1024) void k_combo0(
    const float4* __restrict__ Psort, const float4* __restrict__ P2,
    int n, int m2, int* __restrict__ fpsI,
    const float* __restrict__ p0, const float* __restrict__ x0,
    const float* __restrict__ W1, const float* __restrict__ g1,
    const float* __restrict__ b1, float* __restrict__ X1, int N, int B) {
  __shared__ double skeys[32];
  __shared__ float4 sQ[8192];  // 128 KiB
  __shared__ int sidx[2048];   // 8 KiB
  int bid = blockIdx.x;
  if (bid < B) { fps_body<8, 16>(Psort, P2, n, m2, fpsI, bid, skeys, sQ, sidx); return; }
  enc1_body(p0, x0, W1, g1, b1, X1, N, (bid - B) * 1024 + threadIdx.x);
}

// combo1: fps3 || knn2
__global__ __launch_bounds__(512) void k_combo1(
    const float4* __restrict__ Psort, const float4* __restrict__ P3,
    int m2, int m3, int* __restrict__ fpsI,
    const float4* __restrict__ P2, int n, int* __restrict__ knnA,
    int B, int totq) {
  __shared__ double skeys[32];
  __shared__ float4 sQ[2048];  // 32 KiB
  __shared__ int sidx[512];
  int bid = blockIdx.x;
  if (bid < B) { fps_body<4, 8>(Psort, P3, m2, m3, fpsI, bid, skeys, sQ, sidx); return; }
  int gw = (bid - B) * 8 + (threadIdx.x >> 6);
  if (gw < totq) knn_body(P3, P2, n, m2, knnA, gw);
}

// combo2: fps4 || knn3 || feat2
__global__ __launch_bounds__(256) void k_combo2(
    const float4* __restrict__ Psort, const float4* __restrict__ P4s,
    int m3, int m4, int* __restrict__ fpsI,
    const float4* __restrict__ P3, int m2, int* __restrict__ knnB,
    const float4* __restrict__ P2, const float* __restrict__ X1,
    const int* __restrict__ knnA,
    const float* __restrict__ W2, const float* __restrict__ g2,
    const float* __restrict__ b2, float* __restrict__ X2,
    int n, int B, int nkb, int totq3, int totq2) {
  __shared__ double skeys[32];
  __shared__ float4 sQ[512];  // 8 KiB
  __shared__ int sidx[128];
  __shared__ __align__(16) char sfm[4480];  // 4 * 8 * 35 * 4
  int bid = blockIdx.x;
  if (bid < B) { fps_body<2, 4>(Psort, P4s, m3, m4, fpsI, bid, skeys, sQ, sidx); return; }
  bid -= B;
  if (bid < nkb) {
    int gw = bid * 4 + (threadIdx.x >> 6);
    if (gw < totq3) knn_body(P4s, P3, m2, m3, knnB, gw);
    return;
  }
  bid -= nkb;
  feat_body<32, 64, 256>(P3, P2, X1, knnA, W2, g2, b2, X2, n, m2,
                         bid * 4, totq2, sfm);
}

// combo3: fps5 || knn4 || feat3
__global__ __launch_bounds__(128) void k_combo3(
    const float4* __restrict__ Psort, const float4* __restrict__ P5,
    int m4, int m5, int* __restrict__ fpsI,
    const float4* __restrict__ P4s, int m3, int* __restrict__ knnA,
    const float4* __restrict__ P3, const float* __restrict__ X2,
    const int* __restrict__ knnB,
    const float* __restrict__ W3, const float* __restrict__ g3,
    const float* __restrict__ b3, float* __restrict__ X3,
    int m2, int B, int nkb, int totq4, int totq3) {
  __shared__ double skeys[32];
  __shared__ float4 sQ[128];  // 2 KiB
  __shared__ int sidx[32];
  __shared__ __align__(16) char sfm[2144];  // 1 * 8 * 67 * 4
  int bid = blockIdx.x;
  if (bid < B) { fps_body<1, 2>(Psort, P5, m4, m5, fpsI, bid, skeys, sQ, sidx); return; }
  bid -= B;
  if (bid < nkb) {
    int gw = bid * 2 + (threadIdx.x >> 6);
    if (gw < totq4) knn_body(P5, P4s, m3, m4, knnA, gw);
    return;
  }
  bid -= nkb;
  feat_body<64, 128, 128>(P4s, P3, X2, knnB, W3, g3, b3, X3, m2, m3,
                          bid, totq3, sfm);
}

// combo4: knn5 || feat4
__global__ __launch_bounds__(512) void k_combo4(
    const float4* __restrict__ P6, const float4* __restrict__ P5,
    int m4, int m5, int* __restrict__ knnB,
    const float4* __restrict__ P4s, const float* __restrict__ X3,
    const int* __restrict__ knnA,
    const float* __restrict__ W4, const float* __restrict__ g4,
    const float* __restrict__ b4, float* __restrict__ X4,
    int m3, int nkb, int totq5, int totq4) {
  __shared__ __align__(16) char sfm[8384];  // 2 * 8 * 131 * 4
  int bid = blockIdx.x;
  if (bid < nkb) {
    int gw = bid * 8 + (threadIdx.x >> 6);
    if (gw < totq5) knn_body(P6, P5, m4, m5, knnB, gw);
    return;
  }
  bid -= nkb;
  feat_body<128, 256, 512>(P5, P4s, X3, knnA, W4, g4, b4, X4, m3, m4,
                           bid * 2, totq4, sfm);
}

// ---------------- gather sampled points (bit-identical copy) ----------------
__global__ void k_gather(const float4* __restrict__ Pin, const int* __restrict__ idx,
                         float4* __restrict__ Pout, int n, int m, int total) {
  int t = blockIdx.x * blockDim.x + threadIdx.x;
  if (t >= total) return;
  int b = t / m;
  Pout[t] = Pin[(size_t)b * n + idx[t]];
}

// ---------------- feat5 standalone (CINF=256, COUT=512) ----------------
__global__ __launch_bounds__(512) void k_feat5(
    const float4* __restrict__ Pq, const float4* __restrict__ Pc,
    const float* __restrict__ Xin, const int* __restrict__ knn,
    const float* __restrict__ W, const float* __restrict__ g,
    const float* __restrict__ bt, float* __restrict__ Xout, int n, int m) {
  __shared__ __align__(16) char sfm[8 * 259 * 4];
  feat_body<256, 512, 512>(Pq, Pc, Xin, knn, W, g, bt, Xout, n, m,
                           blockIdx.x, gridDim.x, sfm);
}

// ---------------- head: mean-pool + fc/bn/relu + fc ----------------
__global__ __launch_bounds__(512) void k_head(
    const float* __restrict__ X5, const float* __restrict__ Wc1, const float* __restrict__ bc1,
    const float* __restrict__ gc, const float* __restrict__ bcl,
    const float* __restrict__ Wc2, const float* __restrict__ bc2,
    float* __restrict__ out, int m5) {
  __shared__ float sp[512];
  __shared__ float sh[256];
  int b = blockIdx.x, tid = threadIdx.x;
  float s = 0.f;
  for (int i = 0; i < m5; ++i) s += X5[((size_t)b * m5 + i) * 512 + tid];
  sp[tid] = s * (1.0f / m5);
  __syncthreads();
  if (tid < 256) {
    float a = bc1[tid];
    for (int j = 0; j < 512; ++j) a = fmaf(sp[j], Wc1[j * 256 + tid], a);
    a = a * (gc[tid] * BNI) + bcl[tid];
    sh[tid] = fmaxf(a, 0.f);
  }
  __syncthreads();
  if (tid < 40) {
    float a = bc2[tid];
    for (int j = 0; j < 256; ++j) a = fmaf(sh[j], Wc2[j * 40 + tid], a);
    out[b * 40 + tid] = a;
  }
}

extern "C" void kernel_launch(void* const* d_in, const int* in_sizes, int n_in,
                              void* d_out, int out_size, void* d_ws, size_t ws_size,
                              hipStream_t stream) {
  const float* p0 = (const float*)d_in[0];
  const float* x0 = (const float*)d_in[1];
  const int B = in_sizes[2];
  const int N = in_sizes[0] / 3;
  const int n = N / B;  // 8192
  const float* W1 = (const float*)d_in[3];
  const float* g1 = (const float*)d_in[4];
  const float* b1 = (const float*)d_in[5];
  const float* W2 = (const float*)d_in[6];
  const float* g2 = (const float*)d_in[7];
  const float* b2 = (const float*)d_in[8];
  const float* W3 = (const float*)d_in[9];
  const float* g3 = (const float*)d_in[10];
  const float* b3 = (const float*)d_in[11];
  const float* W4 = (const float*)d_in[12];
  const float* g4 = (const float*)d_in[13];
  const float* b4 = (const float*)d_in[14];
  const float* W5 = (const float*)d_in[15];
  const float* g5 = (const float*)d_in[16];
  const float* b5 = (const float*)d_in[17];
  const float* Wc1 = (const float*)d_in[18];
  const float* bc1 = (const float*)d_in[19];
  const float* gcls = (const float*)d_in[20];
  const float* bcls = (const float*)d_in[21];
  const float* Wc2 = (const float*)d_in[22];
  const float* bc2 = (const float*)d_in[23];
  float* out = (float*)d_out;

  const int m2 = n / 4, m3 = m2 / 4, m4 = m3 / 4, m5 = m4 / 4;

  char* ws = (char*)d_ws;
  size_t off = 0;
  auto alloc = [&](size_t bytes) -> void* {
    void* p = ws + off;
    off += (bytes + 255) & ~(size_t)255;
    return p;
  };
  float4* P2 = (float4*)alloc((size_t)N * 16);
  float* X1 = (float*)alloc((size_t)N * 32 * 4);
  float4* P3 = (float4*)alloc((size_t)B * m2 * 16);
  float4* P4s = (float4*)alloc((size_t)B * m3 * 16);
  float4* P5 = (float4*)alloc((size_t)B * m4 * 16);
  float4* P6 = (float4*)alloc((size_t)B * m5 * 16);
  int* fpsI = (int*)alloc((size_t)B * m2 * 4);
  int* knnA = (int*)alloc((size_t)B * m2 * 8 * 4);  // stages 2 and 4
  int* knnB = (int*)alloc((size_t)B * m3 * 8 * 4);  // stages 3 and 5
  float* X2 = (float*)alloc((size_t)B * m2 * 64 * 4);
  float* X3 = (float*)alloc((size_t)B * m3 * 128 * 4);
  float* X4 = (float*)alloc((size_t)B * m4 * 256 * 4);
  float* X5 = (float*)alloc((size_t)B * m5 * 512 * 4);
  float4* Psort = (float4*)alloc((size_t)N * 16);

  k_prep<<<(N + 255) / 256, 256, 0, stream>>>(p0, P2, N);

  // stage 2: sort, then fps2 || enc1
  k_sortgather<8192, false><<<B, 1024, 0, stream>>>(P2, nullptr, 0, nullptr, Psort);
  {
    int eb = (N * 32 + 1023) / 1024;
    k_combo0<<<B + eb, 1024, 0, stream>>>(Psort, P2, n, m2, fpsI,
                                          p0, x0, W1, g1, b1, X1, N, B);
  }

  // stage 3: gather+sort, then fps3 || knn2
  k_sortgather<2048, true><<<B, 1024, 0, stream>>>(P2, fpsI, n, P3, Psort);
  {
    int kb = (B * m2 + 7) / 8;
    k_combo1<<<B + kb, 512, 0, stream>>>(Psort, P3, m2, m3, fpsI,
                                         P2, n, knnA, B, B * m2);
  }

  // stage 4: gather+sort, then fps4 || knn3 || feat2
  k_sortgather<512, true><<<B, 1024, 0, stream>>>(P3, fpsI, m2, P4s, Psort);
  {
    int nkb = (B * m3 + 3) / 4;
    int fb = (B * m2 + 3) / 4;
    k_combo2<<<B + nkb + fb, 256, 0, stream>>>(
        Psort, P4s, m3, m4, fpsI, P3, m2, knnB, P2, X1, knnA,
        W2, g2, b2, X2, n, B, nkb, B * m3, B * m2);
  }

  // stage 5: gather+sort, then fps5 || knn4 || feat3
  k_sortgather<128, true><<<B, 1024, 0, stream>>>(P4s, fpsI, m3, P5, Psort);
  {
    int nkb = (B * m4 + 1) / 2;
    int fb = B * m3;
    k_combo3<<<B + nkb + fb, 128, 0, stream>>>(
        Psort, P5, m4, m5, fpsI, P4s, m3, knnA, P3, X2, knnB,
        W3, g3, b3, X3, m2, B, nkb, B * m4, B * m3);
  }
  k_gather<<<(B * m5 + 255) / 256, 256, 0, stream>>>(P5, fpsI, P6, m4, m5, B * m5);

  // knn5 || feat4
  {
    int nkb = (B * m5 + 7) / 8;
    int fb = (B * m4 + 1) / 2;
    k_combo4<<<nkb + fb, 512, 0, stream>>>(
        P6, P5, m4, m5, knnB, P4s, X3, knnA,
        W4, g4, b4, X4, m3, nkb, B * m5, B * m4);
  }

  // feat5, head
  k_feat5<<<B * m5, 512, 0, stream>>>(P6, P5, X4, knnB, W5, g5, b5, X5, m4, m5);
  k_head<<<B, 512, 0, stream>>>(X5, Wc1, bc1, gcls, bcls, Wc2, bc2, out, m5);
}

// Round 14
// 2165.130 us; speedup vs baseline: 1.0348x; 1.0348x over previous
//
#include <hip/hip_runtime.h>
#include <float.h>

#define BNI 0.9999950000374997f  /* 1/sqrt(1+1e-5) */

typedef unsigned int v2u __attribute__((ext_vector_type(2)));

__device__ __forceinline__ float sq3(float x, float y, float z) {
  // exact numpy semantics: (x*x + y*y) + z*z, no FMA contraction
  return __fadd_rn(__fadd_rn(__fmul_rn(x, x), __fmul_rn(y, y)), __fmul_rn(z, z));
}

// ---- packed argmax key: (float_bits(v) << 32) | ~idx, as positive f64 ----
// v >= 0 -> positive double; f64 max ordering == u64 ordering.
// Ties in v resolve to larger ~idx == smaller orig idx (numpy first-max).
// Keys globally unique (distinct ~idx).
__device__ __forceinline__ int key_idx(double k) { return ~__double2loint(k); }

template <int CTRL>
__device__ __forceinline__ double dpp_max(double k) {
  union { double d; int i[2]; } u, r;
  u.d = k;
  r.i[0] = __builtin_amdgcn_mov_dpp(u.i[0], CTRL, 0xF, 0xF, true);
  r.i[1] = __builtin_amdgcn_mov_dpp(u.i[1], CTRL, 0xF, 0xF, true);
  return fmax(k, r.d);
}
// 16-group / 32-half swaps via gfx950 permlane (VALU-speed, no DS round-trip).
// With a==b both outputs hold the partner value; max over BOTH is exact.
// Validated bit-exact in rounds 5-13.
__device__ __forceinline__ double pl16_kmax(double k) {
  union { double d; unsigned i[2]; } u; u.d = k;
  v2u a0 = __builtin_amdgcn_permlane16_swap(u.i[0], u.i[0], false, false);
  v2u a1 = __builtin_amdgcn_permlane16_swap(u.i[1], u.i[1], false, false);
  k = fmax(k, __hiloint2double((int)a1[0], (int)a0[0]));
  k = fmax(k, __hiloint2double((int)a1[1], (int)a0[1]));
  return k;
}
__device__ __forceinline__ double pl32_kmax(double k) {
  union { double d; unsigned i[2]; } u; u.d = k;
  v2u a0 = __builtin_amdgcn_permlane32_swap(u.i[0], u.i[0], false, false);
  v2u a1 = __builtin_amdgcn_permlane32_swap(u.i[1], u.i[1], false, false);
  k = fmax(k, __hiloint2double((int)a1[0], (int)a0[0]));
  k = fmax(k, __hiloint2double((int)a1[1], (int)a0[1]));
  return k;
}
// full 64-lane key max, all-lane replicated, all-VALU
__device__ __forceinline__ double wave_max_key(double k) {
  k = dpp_max<0xB1>(k);   // xor 1
  k = dpp_max<0x4E>(k);   // xor 2
  k = dpp_max<0x141>(k);  // row_half_mirror : 4 -> 8
  k = dpp_max<0x140>(k);  // row_mirror      : 8 -> 16
  k = pl16_kmax(k);       // 16-group swap
  k = pl32_kmax(k);       // 32-half swap
  return k;
}

// ---------------- prep: P4[i] = (x,y,z, x^2+y^2+z^2) ----------------
__global__ void k_prep(const float* __restrict__ p, float4* __restrict__ P4, int N) {
  int i = blockIdx.x * blockDim.x + threadIdx.x;
  if (i < N) {
    float x = p[3 * i], y = p[3 * i + 1], z = p[3 * i + 2];
    P4[i] = make_float4(x, y, z, sq3(x, y, z));
  }
}

// ================= fused gather + Morton 8^3 counting sort =================
// One block per batch: gather (optional) -> LDS -> bbox -> hist -> scan ->
// scatter. Scatter order in a cell is nondeterministic; FPS output is
// permutation-invariant (max with original-index tie-break) -> bit-exact.
__device__ __forceinline__ unsigned mpart3(unsigned x) {
  return (x & 1u) | ((x & 2u) << 2) | ((x & 4u) << 4);
}
__device__ __forceinline__ int cell_id(float4 v, const float* bb) {
  int cx = min(max((int)((v.x - bb[0]) * bb[3]), 0), 7);
  int cy = min(max((int)((v.y - bb[1]) * bb[4]), 0), 7);
  int cz = min(max((int)((v.z - bb[2]) * bb[5]), 0), 7);
  return (int)((mpart3(cx) << 2) | (mpart3(cy) << 1) | mpart3(cz));
}

template <int NPTS, bool DOGATHER>
__global__ __launch_bounds__(1024) void k_sortgather(
    const float4* __restrict__ Pin, const int* __restrict__ fpsI, int n_prev,
    float4* __restrict__ Pout, float4* __restrict__ Psort) {
  __shared__ float4 sPts[NPTS];
  __shared__ int sHist[512], sScan[512], sCur[512];
  __shared__ float sBB[6][16];
  __shared__ float sBBf[8];
  const int b = blockIdx.x, tid = threadIdx.x;
  const int lane = tid & 63, wid = tid >> 6;
  for (int i = tid; i < NPTS; i += 1024) {
    float4 v;
    if (DOGATHER) {
      int src = fpsI[(size_t)b * NPTS + i];
      v = Pin[(size_t)b * n_prev + src];
      Pout[(size_t)b * NPTS + i] = v;  // publish gathered points (bit-copy)
    } else {
      v = Pin[(size_t)b * NPTS + i];
    }
    sPts[i] = v;
  }
  if (tid < 512) sHist[tid] = 0;
  __syncthreads();
  float lx = FLT_MAX, hx = -FLT_MAX, ly = FLT_MAX, hy = -FLT_MAX, lz = FLT_MAX, hz = -FLT_MAX;
  for (int i = tid; i < NPTS; i += 1024) {
    float4 v = sPts[i];
    lx = fminf(lx, v.x); hx = fmaxf(hx, v.x);
    ly = fminf(ly, v.y); hy = fmaxf(hy, v.y);
    lz = fminf(lz, v.z); hz = fmaxf(hz, v.z);
  }
#pragma unroll
  for (int off = 1; off < 64; off <<= 1) {
    lx = fminf(lx, __shfl_xor(lx, off)); hx = fmaxf(hx, __shfl_xor(hx, off));
    ly = fminf(ly, __shfl_xor(ly, off)); hy = fmaxf(hy, __shfl_xor(hy, off));
    lz = fminf(lz, __shfl_xor(lz, off)); hz = fmaxf(hz, __shfl_xor(hz, off));
  }
  if (lane == 0) {
    sBB[0][wid] = lx; sBB[1][wid] = hx; sBB[2][wid] = ly;
    sBB[3][wid] = hy; sBB[4][wid] = lz; sBB[5][wid] = hz;
  }
  __syncthreads();
  if (tid == 0) {
    float LX = FLT_MAX, HX = -FLT_MAX, LY = FLT_MAX, HY = -FLT_MAX, LZ = FLT_MAX, HZ = -FLT_MAX;
    for (int w = 0; w < 16; ++w) {
      LX = fminf(LX, sBB[0][w]); HX = fmaxf(HX, sBB[1][w]);
      LY = fminf(LY, sBB[2][w]); HY = fmaxf(HY, sBB[3][w]);
      LZ = fminf(LZ, sBB[4][w]); HZ = fmaxf(HZ, sBB[5][w]);
    }
    float ex = HX - LX, ey = HY - LY, ez = HZ - LZ;
    sBBf[0] = LX; sBBf[1] = LY; sBBf[2] = LZ;
    sBBf[3] = ex > 0.f ? 8.f / ex : 0.f;
    sBBf[4] = ey > 0.f ? 8.f / ey : 0.f;
    sBBf[5] = ez > 0.f ? 8.f / ez : 0.f;
  }
  __syncthreads();
  for (int i = tid; i < NPTS; i += 1024)
    atomicAdd(&sHist[cell_id(sPts[i], sBBf)], 1);
  __syncthreads();
  if (tid < 512) sScan[tid] = sHist[tid];
  __syncthreads();
  for (int d = 1; d < 512; d <<= 1) {
    int v = 0;
    if (tid < 512 && tid >= d) v = sScan[tid - d];
    __syncthreads();
    if (tid < 512) sScan[tid] += v;
    __syncthreads();
  }
  if (tid < 512) sCur[tid] = sScan[tid] - sHist[tid];  // exclusive
  __syncthreads();
  for (int i = tid; i < NPTS; i += 1024) {
    float4 v = sPts[i];
    int pos = atomicAdd(&sCur[cell_id(v, sBBf)], 1);
    Psort[(size_t)b * NPTS + pos] = make_float4(v.x, v.y, v.z, __int_as_float(i));
  }
}

// ============ FPS body — R10/R12 champion verbatim (1641 us measured) ========
// Wave w owns sorted [w*64*PT,(w+1)*64*PT); wave bbox prune; skip == provable
// no-op (monotone rn ops); unique packed keys -> bit-exact vs numpy.
// sQ: LDS copy of coords indexed by ORIGINAL index (scattered at init) so the
// per-step winner-coords fetch is a uniform ds_read_b128, not an L2 load.
template <int PT, int NW>
__device__ __forceinline__ void fps_body(
    const float4* __restrict__ Psort, const float4* __restrict__ Porig,
    int n, int m, int* __restrict__ out_idx, int b, double* keys /*[2*16]*/,
    float4* sQ) {
  const int tid = threadIdx.x;
  const int lane = tid & 63, wid = tid >> 6;
  const float4* PS = Psort + (size_t)b * n;
  const float4* PO = Porig + (size_t)b * n;

  float px[PT], py[PT], pz[PT], dist[PT];
  int ni[PT];  // ~orig_idx per slot
  const int base = wid * (64 * PT);
#pragma unroll
  for (int k = 0; k < PT; ++k) {
    float4 v = PS[base + k * 64 + lane];
    px[k] = v.x; py[k] = v.y; pz[k] = v.z;
    int oi = __float_as_int(v.w);
    ni[k] = ~oi;
    sQ[oi] = make_float4(v.x, v.y, v.z, 0.f);  // coords by orig idx (bit-copy)
  }
  // wave bbox (one-time)
  float lx = px[0], hx = px[0], ly = py[0], hy = py[0], lz = pz[0], hz = pz[0];
#pragma unroll
  for (int k = 1; k < PT; ++k) {
    lx = fminf(lx, px[k]); hx = fmaxf(hx, px[k]);
    ly = fminf(ly, py[k]); hy = fmaxf(hy, py[k]);
    lz = fminf(lz, pz[k]); hz = fmaxf(hz, pz[k]);
  }
#pragma unroll
  for (int off = 1; off < 64; off <<= 1) {
    lx = fminf(lx, __shfl_xor(lx, off)); hx = fmaxf(hx, __shfl_xor(hx, off));
    ly = fminf(ly, __shfl_xor(ly, off)); hy = fmaxf(hy, __shfl_xor(hy, off));
    lz = fminf(lz, __shfl_xor(lz, off)); hz = fmaxf(hz, __shfl_xor(hz, off));
  }
  if (tid == 0) out_idx[(size_t)b * m] = 0;

  float4 q0 = PO[0];
  double ck[PT];
#pragma unroll
  for (int k = 0; k < PT; ++k) {
    float d = sq3(__fsub_rn(px[k], q0.x), __fsub_rn(py[k], q0.y), __fsub_rn(pz[k], q0.z));
    dist[k] = d;
    ck[k] = __hiloint2double(__float_as_int(d), ni[k]);
  }
#pragma unroll
  for (int s = 1; s < PT; s <<= 1)  // exact tree reorder of max over unique keys
#pragma unroll
    for (int k = 0; k + s < PT; k += 2 * s) ck[k] = fmax(ck[k], ck[k + s]);
  double wkey = wave_max_key(ck[0]);

  for (int t = 1; t < m; ++t) {
    int buf = t & 1;  // double-buffered publish -> single barrier per step
    if (lane == 0) keys[buf * 16 + wid] = wkey;
    __syncthreads();
    double kb = keys[buf * 16 + (lane & (NW - 1))];  // replicated broadcast read
    if (NW >= 2)  kb = dpp_max<0xB1>(kb);
    if (NW >= 4)  kb = dpp_max<0x4E>(kb);
    if (NW >= 8)  kb = dpp_max<0x141>(kb);
    if (NW >= 16) kb = dpp_max<0x140>(kb);
    int wi = key_idx(kb);
    if (tid == 0) out_idx[(size_t)b * m + t] = wi;
    if (t + 1 >= m) break;
    float4 qq = sQ[wi];  // uniform LDS broadcast read (init scatter, pre-barrier)
    // exact lower bound of d2 from this wave's bbox to qq (monotone rn ops)
    float tx = fmaxf(fmaxf(__fsub_rn(lx, qq.x), __fsub_rn(qq.x, hx)), 0.f);
    float ty = fmaxf(fmaxf(__fsub_rn(ly, qq.y), __fsub_rn(qq.y, hy)), 0.f);
    float tz = fmaxf(fmaxf(__fsub_rn(lz, qq.z), __fsub_rn(qq.z, hz)), 0.f);
    float lb = sq3(tx, ty, tz);
    float wv = __uint_as_float((unsigned)__double2hiint(wkey));
    if (lb < wv) {  // wave-uniform; prune == provable no-op
      double ck2[PT];
#pragma unroll
      for (int k = 0; k < PT; ++k) {
        float d = sq3(__fsub_rn(px[k], qq.x), __fsub_rn(py[k], qq.y), __fsub_rn(pz[k], qq.z));
        float nd = fminf(dist[k], d);
        dist[k] = nd;
        ck2[k] = __hiloint2double(__float_as_int(nd), ni[k]);
      }
#pragma unroll
      for (int s = 1; s < PT; s <<= 1)
#pragma unroll
        for (int k = 0; k + s < PT; k += 2 * s) ck2[k] = fmax(ck2[k], ck2[k + s]);
      wkey = wave_max_key(ck2[0]);
    }
  }
}

// ---------------- enc1 body (elementwise, used by combo0 extra blocks) -------
__device__ __forceinline__ void enc1_body(
    const float* __restrict__ p0, const float* __restrict__ x0,
    const float* __restrict__ W, const float* __restrict__ g,
    const float* __restrict__ bt, float* __restrict__ X, int N, int t) {
  int pt = t >> 5, c = t & 31;
  if (pt >= N) return;
  float i0 = p0[pt * 3], i1 = p0[pt * 3 + 1], i2 = p0[pt * 3 + 2];
  float i3 = x0[pt * 3], i4 = x0[pt * 3 + 1], i5 = x0[pt * 3 + 2];
  float a = i0 * W[c] + i1 * W[32 + c] + i2 * W[64 + c] +
            i3 * W[96 + c] + i4 * W[128 + c] + i5 * W[160 + c];
  a = a * (g[c] * BNI) + bt[c];
  X[(size_t)pt * 32 + c] = fmaxf(a, 0.f);
}

// ---------------- KNN body: one wave per query; exact expanded-form d2 -------
__device__ void knn_body(const float4* __restrict__ Pq, const float4* __restrict__ Pc,
                         int n, int m, int* __restrict__ knn, int gw) {
  int lane = threadIdx.x & 63;
  int b = gw / m;
  float4 q = Pq[gw];
  const float4* C = Pc + (size_t)b * n;
  float ad[8];
  int ai[8];
#pragma unroll
  for (int s = 0; s < 8; ++s) { ad[s] = FLT_MAX; ai[s] = 0x7fffffff; }
  for (int j = lane; j < n; j += 64) {
    float4 c = C[j];
    float dot = __fadd_rn(__fadd_rn(__fmul_rn(q.x, c.x), __fmul_rn(q.y, c.y)), __fmul_rn(q.z, c.z));
    float d2 = __fsub_rn(__fadd_rn(q.w, c.w), __fmul_rn(2.f, dot));  // (qq+pp) - 2*dot
    if (d2 < ad[7] || (d2 == ad[7] && j < ai[7])) {
      float cd = d2; int ci = j;
#pragma unroll
      for (int s = 0; s < 8; ++s) {
        bool sw = (cd < ad[s]) || (cd == ad[s] && ci < ai[s]);
        float td = ad[s]; int ti = ai[s];
        ad[s] = sw ? cd : td; ai[s] = sw ? ci : ti;
        cd = sw ? td : cd;  ci = sw ? ti : ci;
      }
    }
  }
  int pos = 0;
  int* kout = knn + (size_t)gw * 8;
#pragma unroll
  for (int r = 0; r < 8; ++r) {
    float hv = FLT_MAX; int hi = 0x7fffffff;
#pragma unroll
    for (int s = 7; s >= 0; --s)
      if (pos == s) { hv = ad[s]; hi = ai[s]; }
    float v = hv; int ix = hi;
#pragma unroll
    for (int off = 1; off < 64; off <<= 1) {
      float ov = __shfl_xor(v, off);
      int oi = __shfl_xor(ix, off);
      if (ov < v || (ov == v && oi < ix)) { v = ov; ix = oi; }
    }
    if (hv == v && hi == ix) pos++;  // unique owner (point indices unique)
    if (lane == 0) kout[r] = ix;
  }
}

// ------- feat body: NQ = NT/COUT queries per block, same math as before ------
template <int CINF, int COUT, int NT>
__device__ __forceinline__ void feat_body(
    const float4* __restrict__ Pq, const float4* __restrict__ Pc,
    const float* __restrict__ Xin, const int* __restrict__ knn,
    const float* __restrict__ W, const float* __restrict__ g,
    const float* __restrict__ bt, float* __restrict__ Xout,
    int n, int m, int bi0, int total, char* smem) {
  constexpr int F = 3 + CINF;
  constexpr int NQ = NT / COUT;
  typedef float SF[8][F];
  SF* sf = (SF*)smem;
  int tid = threadIdx.x;
  if (tid < NQ * 8) {
    int ql = tid >> 3, k = tid & 7;
    int bi = bi0 + ql;
    if (bi < total) {
      float4 q = Pq[bi];
      int b = bi / m;
      int nb = knn[(size_t)bi * 8 + k];
      float4 c = Pc[(size_t)b * n + nb];
      sf[ql][k][0] = c.x - q.x;
      sf[ql][k][1] = c.y - q.y;
      sf[ql][k][2] = c.z - q.z;
    }
  }
  for (int e = tid; e < NQ * 8 * CINF; e += NT) {
    int ql = e / (8 * CINF);
    int r = e - ql * (8 * CINF);
    int k = r / CINF, j = r - k * CINF;
    int bi = bi0 + ql;
    if (bi < total) {
      int b = bi / m;
      int nb = knn[(size_t)bi * 8 + k];
      sf[ql][k][3 + j] = Xin[((size_t)b * n + nb) * CINF + j];
    }
  }
  __syncthreads();
  int ql = tid / COUT, c = tid - ql * COUT;
  int bi = bi0 + ql;
  if (bi >= total) return;
  float acc[8] = {0.f, 0.f, 0.f, 0.f, 0.f, 0.f, 0.f, 0.f};
  for (int j = 0; j < F; ++j) {
    float w = W[(size_t)j * COUT + c];
#pragma unroll
    for (int k = 0; k < 8; ++k) acc[k] = fmaf(sf[ql][k][j], w, acc[k]);
  }
  float sc = g[c] * BNI, bb = bt[c];
  float mx = 0.f;
#pragma unroll
  for (int k = 0; k < 8; ++k) mx = fmaxf(mx, fmaf(acc[k], sc, bb));
  Xout[(size_t)bi * COUT + c] = mx;
}

// ======================= fused heterogeneous kernels =========================
// combo0: fps2 (blocks 0..B-1) || enc1
__global__ __launch_bounds__(1024) void k_combo0(
    const float4* __restrict__ Psort, const float4* __restrict__ P2,
    int n, int m2, int* __restrict__ fpsI,
    const float* __restrict__ p0, const float* __restrict__ x0,
    const float* __restrict__ W1, const float* __restrict__ g1,
    const float* __restrict__ b1, float* __restrict__ X1, int N, int B) {
  __shared__ double skeys[32];
  __shared__ float4 sQ[8192];  // 128 KiB
  int bid = blockIdx.x;
  if (bid < B) { fps_body<8, 16>(Psort, P2, n, m2, fpsI, bid, skeys, sQ); return; }
  enc1_body(p0, x0, W1, g1, b1, X1, N, (bid - B) * 1024 + threadIdx.x);
}

// combo1: fps3 || knn2
__global__ __launch_bounds__(512) void k_combo1(
    const float4* __restrict__ Psort, const float4* __restrict__ P3,
    int m2, int m3, int* __restrict__ fpsI,
    const float4* __restrict__ P2, int n, int* __restrict__ knnA,
    int B, int totq) {
  __shared__ double skeys[32];
  __shared__ float4 sQ[2048];  // 32 KiB
  int bid = blockIdx.x;
  if (bid < B) { fps_body<4, 8>(Psort, P3, m2, m3, fpsI, bid, skeys, sQ); return; }
  int gw = (bid - B) * 8 + (threadIdx.x >> 6);
  if (gw < totq) knn_body(P3, P2, n, m2, knnA, gw);
}

// combo2: fps4 || knn3 || feat2
__global__ __launch_bounds__(256) void k_combo2(
    const float4* __restrict__ Psort, const float4* __restrict__ P4s,
    int m3, int m4, int* __restrict__ fpsI,
    const float4* __restrict__ P3, int m2, int* __restrict__ knnB,
    const float4* __restrict__ P2, const float* __restrict__ X1,
    const int* __restrict__ knnA,
    const float* __restrict__ W2, const float* __restrict__ g2,
    const float* __restrict__ b2, float* __restrict__ X2,
    int n, int B, int nkb, int totq3, int totq2) {
  __shared__ double skeys[32];
  __shared__ float4 sQ[512];  // 8 KiB
  __shared__ __align__(16) char sfm[4480];  // 4 * 8 * 35 * 4
  int bid = blockIdx.x;
  if (bid < B) { fps_body<2, 4>(Psort, P4s, m3, m4, fpsI, bid, skeys, sQ); return; }
  bid -= B;
  if (bid < nkb) {
    int gw = bid * 4 + (threadIdx.x >> 6);
    if (gw < totq3) knn_body(P4s, P3, m2, m3, knnB, gw);
    return;
  }
  bid -= nkb;
  feat_body<32, 64, 256>(P3, P2, X1, knnA, W2, g2, b2, X2, n, m2,
                         bid * 4, totq2, sfm);
}

// combo3: fps5 || knn4 || feat3
__global__ __launch_bounds__(128) void k_combo3(
    const float4* __restrict__ Psort, const float4* __restrict__ P5,
    int m4, int m5, int* __restrict__ fpsI,
    const float4* __restrict__ P4s, int m3, int* __restrict__ knnA,
    const float4* __restrict__ P3, const float* __restrict__ X2,
    const int* __restrict__ knnB,
    const float* __restrict__ W3, const float* __restrict__ g3,
    const float* __restrict__ b3, float* __restrict__ X3,
    int m2, int B, int nkb, int totq4, int totq3) {
  __shared__ double skeys[32];
  __shared__ float4 sQ[128];  // 2 KiB
  __shared__ __align__(16) char sfm[2144];  // 1 * 8 * 67 * 4
  int bid = blockIdx.x;
  if (bid < B) { fps_body<1, 2>(Psort, P5, m4, m5, fpsI, bid, skeys, sQ); return; }
  bid -= B;
  if (bid < nkb) {
    int gw = bid * 2 + (threadIdx.x >> 6);
    if (gw < totq4) knn_body(P5, P4s, m3, m4, knnA, gw);
    return;
  }
  bid -= nkb;
  feat_body<64, 128, 128>(P4s, P3, X2, knnB, W3, g3, b3, X3, m2, m3,
                          bid, totq3, sfm);
}

// combo4: knn5 || feat4
__global__ __launch_bounds__(512) void k_combo4(
    const float4* __restrict__ P6, const float4* __restrict__ P5,
    int m4, int m5, int* __restrict__ knnB,
    const float4* __restrict__ P4s, const float* __restrict__ X3,
    const int* __restrict__ knnA,
    const float* __restrict__ W4, const float* __restrict__ g4,
    const float* __restrict__ b4, float* __restrict__ X4,
    int m3, int nkb, int totq5, int totq4) {
  __shared__ __align__(16) char sfm[8384];  // 2 * 8 * 131 * 4
  int bid = blockIdx.x;
  if (bid < nkb) {
    int gw = bid * 8 + (threadIdx.x >> 6);
    if (gw < totq5) knn_body(P6, P5, m4, m5, knnB, gw);
    return;
  }
  bid -= nkb;
  feat_body<128, 256, 512>(P5, P4s, X3, knnA, W4, g4, b4, X4, m3, m4,
                           bid * 2, totq4, sfm);
}

// ---------------- gather sampled points (bit-identical copy) ----------------
__global__ void k_gather(const float4* __restrict__ Pin, const int* __restrict__ idx,
                         float4* __restrict__ Pout, int n, int m, int total) {
  int t = blockIdx.x * blockDim.x + threadIdx.x;
  if (t >= total) return;
  int b = t / m;
  Pout[t] = Pin[(size_t)b * n + idx[t]];
}

// ---------------- feat5 standalone (CINF=256, COUT=512) ----------------
__global__ __launch_bounds__(512) void k_feat5(
    const float4* __restrict__ Pq, const float4* __restrict__ Pc,
    const float* __restrict__ Xin, const int* __restrict__ knn,
    const float* __restrict__ W, const float* __restrict__ g,
    const float* __restrict__ bt, float* __restrict__ Xout, int n, int m) {
  __shared__ __align__(16) char sfm[8 * 259 * 4];
  feat_body<256, 512, 512>(Pq, Pc, Xin, knn, W, g, bt, Xout, n, m,
                           blockIdx.x, gridDim.x, sfm);
}

// ---------------- head: mean-pool + fc/bn/relu + fc ----------------
__global__ __launch_bounds__(512) void k_head(
    const float* __restrict__ X5, const float* __restrict__ Wc1, const float* __restrict__ bc1,
    const float* __restrict__ gc, const float* __restrict__ bcl,
    const float* __restrict__ Wc2, const float* __restrict__ bc2,
    float* __restrict__ out, int m5) {
  __shared__ float sp[512];
  __shared__ float sh[256];
  int b = blockIdx.x, tid = threadIdx.x;
  float s = 0.f;
  for (int i = 0; i < m5; ++i) s += X5[((size_t)b * m5 + i) * 512 + tid];
  sp[tid] = s * (1.0f / m5);
  __syncthreads();
  if (tid < 256) {
    float a = bc1[tid];
    for (int j = 0; j < 512; ++j) a = fmaf(sp[j], Wc1[j * 256 + tid], a);
    a = a * (gc[tid] * BNI) + bcl[tid];
    sh[tid] = fmaxf(a, 0.f);
  }
  __syncthreads();
  if (tid < 40) {
    float a = bc2[tid];
    for (int j = 0; j < 256; ++j) a = fmaf(sh[j], Wc2[j * 40 + tid], a);
    out[b * 40 + tid] = a;
  }
}

extern "C" void kernel_launch(void* const* d_in, const int* in_sizes, int n_in,
                              void* d_out, int out_size, void* d_ws, size_t ws_size,
                              hipStream_t stream) {
  const float* p0 = (const float*)d_in[0];
  const float* x0 = (const float*)d_in[1];
  const int B = in_sizes[2];
  const int N = in_sizes[0] / 3;
  const int n = N / B;  // 8192
  const float* W1 = (const float*)d_in[3];
  const float* g1 = (const float*)d_in[4];
  const float* b1 = (const float*)d_in[5];
  const float* W2 = (const float*)d_in[6];
  const float* g2 = (const float*)d_in[7];
  const float* b2 = (const float*)d_in[8];
  const float* W3 = (const float*)d_in[9];
  const float* g3 = (const float*)d_in[10];
  const float* b3 = (const float*)d_in[11];
  const float* W4 = (const float*)d_in[12];
  const float* g4 = (const float*)d_in[13];
  const float* b4 = (const float*)d_in[14];
  const float* W5 = (const float*)d_in[15];
  const float* g5 = (const float*)d_in[16];
  const float* b5 = (const float*)d_in[17];
  const float* Wc1 = (const float*)d_in[18];
  const float* bc1 = (const float*)d_in[19];
  const float* gcls = (const float*)d_in[20];
  const float* bcls = (const float*)d_in[21];
  const float* Wc2 = (const float*)d_in[22];
  const float* bc2 = (const float*)d_in[23];
  float* out = (float*)d_out;

  const int m2 = n / 4, m3 = m2 / 4, m4 = m3 / 4, m5 = m4 / 4;

  char* ws = (char*)d_ws;
  size_t off = 0;
  auto alloc = [&](size_t bytes) -> void* {
    void* p = ws + off;
    off += (bytes + 255) & ~(size_t)255;
    return p;
  };
  float4* P2 = (float4*)alloc((size_t)N * 16);
  float* X1 = (float*)alloc((size_t)N * 32 * 4);
  float4* P3 = (float4*)alloc((size_t)B * m2 * 16);
  float4* P4s = (float4*)alloc((size_t)B * m3 * 16);
  float4* P5 = (float4*)alloc((size_t)B * m4 * 16);
  float4* P6 = (float4*)alloc((size_t)B * m5 * 16);
  int* fpsI = (int*)alloc((size_t)B * m2 * 4);
  int* knnA = (int*)alloc((size_t)B * m2 * 8 * 4);  // stages 2 and 4
  int* knnB = (int*)alloc((size_t)B * m3 * 8 * 4);  // stages 3 and 5
  float* X2 = (float*)alloc((size_t)B * m2 * 64 * 4);
  float* X3 = (float*)alloc((size_t)B * m3 * 128 * 4);
  float* X4 = (float*)alloc((size_t)B * m4 * 256 * 4);
  float* X5 = (float*)alloc((size_t)B * m5 * 512 * 4);
  float4* Psort = (float4*)alloc((size_t)N * 16);

  k_prep<<<(N + 255) / 256, 256, 0, stream>>>(p0, P2, N);

  // stage 2: sort, then fps2 || enc1
  k_sortgather<8192, false><<<B, 1024, 0, stream>>>(P2, nullptr, 0, nullptr, Psort);
  {
    int eb = (N * 32 + 1023) / 1024;
    k_combo0<<<B + eb, 1024, 0, stream>>>(Psort, P2, n, m2, fpsI,
                                          p0, x0, W1, g1, b1, X1, N, B);
  }

  // stage 3: gather+sort, then fps3 || knn2
  k_sortgather<2048, true><<<B, 1024, 0, stream>>>(P2, fpsI, n, P3, Psort);
  {
    int kb = (B * m2 + 7) / 8;
    k_combo1<<<B + kb, 512, 0, stream>>>(Psort, P3, m2, m3, fpsI,
                                         P2, n, knnA, B, B * m2);
  }

  // stage 4: gather+sort, then fps4 || knn3 || feat2
  k_sortgather<512, true><<<B, 1024, 0, stream>>>(P3, fpsI, m2, P4s, Psort);
  {
    int nkb = (B * m3 + 3) / 4;
    int fb = (B * m2 + 3) / 4;
    k_combo2<<<B + nkb + fb, 256, 0, stream>>>(
        Psort, P4s, m3, m4, fpsI, P3, m2, knnB, P2, X1, knnA,
        W2, g2, b2, X2, n, B, nkb, B * m3, B * m2);
  }

  // stage 5: gather+sort, then fps5 || knn4 || feat3
  k_sortgather<128, true><<<B, 1024, 0, stream>>>(P4s, fpsI, m3, P5, Psort);
  {
    int nkb = (B * m4 + 1) / 2;
    int fb = B * m3;
    k_combo3<<<B + nkb + fb, 128, 0, stream>>>(
        Psort, P5, m4, m5, fpsI, P4s, m3, knnA, P3, X2, knnB,
        W3, g3, b3, X3, m2, B, nkb, B * m4, B * m3);
  }
  k_gather<<<(B * m5 + 255) / 256, 256, 0, stream>>>(P5, fpsI, P6, m4, m5, B * m5);

  // knn5 || feat4
  {
    int nkb = (B * m5 + 7) / 8;
    int fb = (B * m4 + 1) / 2;
    k_combo4<<<nkb + fb, 512, 0, stream>>>(
        P6, P5, m4, m5, knnB, P4s, X3, knnA,
        W4, g4, b4, X4, m3, nkb, B * m5, B * m4);
  }

  // feat5, head
  k_feat5<<<B * m5, 512, 0, stream>>>(P6, P5, X4, knnB, W5, g5, b5, X5, m4, m5);
  k_head<<<B, 512, 0, stream>>>(X5, Wc1, bc1, gcls, bcls, Wc2, bc2, out, m5);
}